// Round 7
// baseline (198.489 us; speedup 1.0000x reference)
//
#include <hip/hip_runtime.h>

// out[t][e] = (W[e][ids[t]] + b[e]) * sqrt(512)
// W: (512, 50257) row-major f32; ids: 32768 int32; out: 32768 x 512 f32.
//
// Round 11: chip-wide READ/WRITE PHASE LOCKING (single-variable test of the
// DRAM turnaround/mixing theory — the only axis not yet varied).
//  - Persistent grid: 512 blocks (exactly 2/CU), each loops over 3-4 items
//    (item = bucket x e-half, 1572 total). All blocks start stage together ->
//    chip-wide alternation of read-pure and write-pure phases, instead of
//    ~500 uncorrelated blocks finely mixing a 100 MB read stream with a
//    64 MB random write stream (the invariant behind 2.3-2.9 TB/s, R4-R10).
//  - Geometry held fixed from R10: VB=64 (256 B aligned reads), ECH=256 with
//    one dwordx4 = 1 KB contiguous store per token per wave, 64 KB tile,
//    512 threads, rotation swizzle via pre-rotated global source (linear DMA
//    dest), token list in registers + wave-uniform readlane.

constexpr int VOCAB = 50257;
constexpr int EMB   = 512;
constexpr int NTOK  = 8 * 4096;
constexpr float SCALE = 22.62741699796952f;  // sqrt(512)

constexpr int VB   = 64;                      // vocab ids per bucket
constexpr int NB   = (VOCAB + VB - 1) / VB;   // 786 buckets
constexpr int CAP  = 96;                      // capacity (mean 41.7, sigma 6.5)
constexpr int ECH  = 256;                     // e-rows per item (e-half)
constexpr int NITEMS = NB * 2;                // 1572 (bucket, e-half) items
constexpr int PGRID  = 512;                   // persistent grid: 2 blocks/CU

// d_ws int layout: counts[NB] | ocount[1] | olist[NTOK] | buckets[NB*CAP]

__global__ __launch_bounds__(256) void build_buckets(
    const int* __restrict__ ids,
    int* __restrict__ counts,
    int* __restrict__ olist,
    int* __restrict__ buckets)
{
    int t = blockIdx.x * 256 + threadIdx.x;
    int id = ids[t];
    int bkt = id >> 6;
    int slot = atomicAdd(&counts[bkt], 1);
    if (slot < CAP) {
        buckets[bkt * CAP + slot] = (t << 6) | (id & 63);
    } else {
        int o = atomicAdd(&counts[NB], 1);
        olist[o] = t;
    }
}

__global__ __launch_bounds__(512) void scatter_persist(
    const float* __restrict__ W,
    const float* __restrict__ bias,
    const int*   __restrict__ counts,
    const int*   __restrict__ buckets,
    const int*   __restrict__ olist,
    const int*   __restrict__ ids,
    float*       __restrict__ out)
{
    __shared__ float tile[ECH * VB];      // exactly 65,536 B

    const int tid  = threadIdx.x;
    const int lane = tid & 63;
    const int w    = tid >> 6;            // wave id 0..7

    // Both e-half bias fragments, preloaded once (branch select, no dyn idx).
    const float4 b4lo = *reinterpret_cast<const float4*>(bias + 4 * lane);
    const float4 b4hi = *reinterpret_cast<const float4*>(bias + ECH + 4 * lane);

    for (int item = blockIdx.x; item < NITEMS; item += PGRID) {
        const int b  = item >> 1;         // bucket
        const int z  = item & 1;          // e-half
        const int e0 = z * ECH;
        const int vstart = min(b * VB, VOCAB - VB);
        const int vadj   = b * VB - vstart;   // 0 except last bucket (47)

        // ---- per-item preloads (read phase) ----
        const int cnt   = min(counts[b], CAP);                 // block-uniform
        const int tok_a = buckets[b * CAP + lane];             // slots 0..63
        const int tok_b = buckets[b * CAP + 64 + (lane & 31)]; // slots 64..95

        // ---- stage: 256 rows x 256 B; wave w rows [w*32, w*32+32) ----
        // Linear LDS dest; source col pre-rotated: slot s of row r holds
        // col (s - (r>>2)) & 63.
        #pragma unroll
        for (int p = 0; p < 32; ++p) {
            const int r = w * 32 + p;
            const int srccol = (lane - (r >> 2)) & 63;
            const float* gp = W + (size_t)(e0 + r) * VOCAB + (vstart + srccol);
            float* lp = &tile[r * VB];
            __builtin_amdgcn_global_load_lds(
                (const __attribute__((address_space(1))) void*)gp,
                (__attribute__((address_space(3))) void*)lp, 4, 0, 0);
        }
        __syncthreads();                  // all waves' DMA drained; tile ready

        // ---- scatter: one token/wave/iter, ONE 1KB-contiguous store ----
        // Read slot (vl + lane) & 63 for rows 4*lane+k: 2-way banked (free).
        const float4 b4 = z ? b4hi : b4lo;
        for (int i = w; i < cnt; i += 8) {
            const int pk = (i < 64) ? __builtin_amdgcn_readlane(tok_a, i)
                                    : __builtin_amdgcn_readlane(tok_b, i - 64);
            const int t  = pk >> 6;
            const int vl = (pk & 63) + vadj;
            const int s  = (vl + lane) & 63;
            float4 o;
            o.x = tile[(4 * lane + 0) * VB + s];
            o.y = tile[(4 * lane + 1) * VB + s];
            o.z = tile[(4 * lane + 2) * VB + s];
            o.w = tile[(4 * lane + 3) * VB + s];
            o.x = (o.x + b4.x) * SCALE;
            o.y = (o.y + b4.y) * SCALE;
            o.z = (o.z + b4.z) * SCALE;
            o.w = (o.w + b4.w) * SCALE;
            *reinterpret_cast<float4*>(out + (size_t)t * EMB + e0 + 4 * lane) = o;
        }

        // ---- overflow fix (expected n == 0): items 0/1 (b==0), per e-half ----
        if (b == 0) {
            int n = counts[NB];
            for (int ww = w; ww < n; ww += 8) {
                int t  = olist[ww];
                int id = ids[t];
                #pragma unroll
                for (int m = 0; m < 4; ++m) {
                    int e = e0 + lane + m * 64;
                    out[(size_t)t * EMB + e] =
                        (W[(size_t)e * VOCAB + id] + bias[e]) * SCALE;
                }
            }
        }

        __syncthreads();                  // protect tile before next stage
    }
}

// Fallback (round-1 kernel) if d_ws is too small.
__global__ __launch_bounds__(256) void embed_gather(
    const int*   __restrict__ ids,
    const float* __restrict__ W,
    const float* __restrict__ b,
    float*       __restrict__ out)
{
    int idx4 = blockIdx.x * blockDim.x + threadIdx.x;
    int t    = idx4 >> 7;
    int e    = (idx4 & 127) << 2;
    int id = ids[t];
    float4 bb = *reinterpret_cast<const float4*>(b + e);
    const float* wcol = W + (size_t)id;
    float4 o;
    o.x = (wcol[(size_t)(e + 0) * VOCAB] + bb.x) * SCALE;
    o.y = (wcol[(size_t)(e + 1) * VOCAB] + bb.y) * SCALE;
    o.z = (wcol[(size_t)(e + 2) * VOCAB] + bb.z) * SCALE;
    o.w = (wcol[(size_t)(e + 3) * VOCAB] + bb.w) * SCALE;
    *reinterpret_cast<float4*>(out + (size_t)idx4 * 4) = o;
}

extern "C" void kernel_launch(void* const* d_in, const int* in_sizes, int n_in,
                              void* d_out, int out_size, void* d_ws, size_t ws_size,
                              hipStream_t stream)
{
    const int*   ids  = (const int*)  d_in[0];
    const float* W    = (const float*)d_in[1];
    const float* bias = (const float*)d_in[2];
    float*       out  = (float*)d_out;

    const size_t ws_ints_needed = (size_t)NB + 1 + NTOK + (size_t)NB * CAP;

    if (ws_size >= ws_ints_needed * sizeof(int)) {
        int* counts  = (int*)d_ws;
        int* olist   = counts + NB + 1;
        int* buckets = olist + NTOK;

        hipMemsetAsync(counts, 0, (NB + 1) * sizeof(int), stream);
        build_buckets<<<NTOK / 256, 256, 0, stream>>>(ids, counts, olist, buckets);
        scatter_persist<<<PGRID, 512, 0, stream>>>(W, bias, counts, buckets,
                                                   olist, ids, out);
    } else {
        constexpr int total4 = NTOK * EMB / 4;
        embed_gather<<<total4 / 256, 256, 0, stream>>>(ids, W, bias, out);
    }
}